// Round 1
// baseline (656.590 us; speedup 1.0000x reference)
//
#include <hip/hip_runtime.h>

#define HB 32
#define HT 256
#define HC 2048
#define HH 16
#define HD 128
#define HM (HB * HT)  // 8192

typedef __bf16 bf16x8 __attribute__((ext_vector_type(8)));
typedef float f32x4 __attribute__((ext_vector_type(4)));

__device__ __forceinline__ unsigned short f2bf(float f) {
  unsigned u = __float_as_uint(f);
  u += 0x7FFFu + ((u >> 16) & 1u);  // round-to-nearest-even
  return (unsigned short)(u >> 16);
}
__device__ __forceinline__ float bf2f(unsigned short h) {
  return __uint_as_float(((unsigned)h) << 16);
}

// ---------------- fp32 -> bf16 convert ----------------
__global__ void cvt_kernel(const float* __restrict__ in, unsigned short* __restrict__ out, int n4) {
  int i = blockIdx.x * blockDim.x + threadIdx.x;
  if (i >= n4) return;
  float4 v = ((const float4*)in)[i];
  ushort4 o;
  o.x = f2bf(v.x); o.y = f2bf(v.y); o.z = f2bf(v.z); o.w = f2bf(v.w);
  ((ushort4*)out)[i] = o;
}

// ---------------- GEMM: C[m,n] = sum_k A[m,k] * W[n,k] ----------------
// A: [M, 2048] bf16 row-major, W: [2048, 2048] bf16 row-major (N rows of K).
// MODE 0: fp32 out [M, 2048]; MODE 1: bf16 out [B,H,T,D]; MODE 2: bf16 out [B,H,D,T].
__device__ __forceinline__ void gl_lds16(const unsigned short* g, unsigned short* l) {
  __builtin_amdgcn_global_load_lds((const __attribute__((address_space(1))) void*)g,
                                   (__attribute__((address_space(3))) void*)l, 16, 0, 0);
}

template <int MODE>
__global__ __launch_bounds__(256) void gemm_bt(const unsigned short* __restrict__ A,
                                               const unsigned short* __restrict__ W,
                                               void* __restrict__ outp) {
  // LDS tiles [128 rows][8 x 16B chunks], XOR-swizzled: lds chunk (row, cc) holds
  // global chunk (row, cc ^ (row&7)). Compatible with global_load_lds (no padding)
  // and conflict-free (2-way max) on ds_read_b128.
  __shared__ __align__(16) unsigned short lsA[128 * 64];
  __shared__ __align__(16) unsigned short lsB[128 * 64];

  const int tid = threadIdx.x;
  const int lane = tid & 63, wave = tid >> 6;
  const int quad = lane >> 4, l16 = lane & 15;
  const int wr = wave >> 1, wc = wave & 1;
  const int bm = blockIdx.x, bn = blockIdx.y;

  f32x4 acc[4][4];
#pragma unroll
  for (int i = 0; i < 4; i++)
#pragma unroll
    for (int j = 0; j < 4; j++) acc[i][j] = f32x4{0.f, 0.f, 0.f, 0.f};

  const unsigned short* Ab = A + (size_t)bm * 128 * HC;
  const unsigned short* Wb = W + (size_t)bn * 128 * HC;

  for (int kt = 0; kt < HC / 64; ++kt) {
    __syncthreads();  // previous iteration's reads done before overwrite
#pragma unroll
    for (int i = 0; i < 4; i++) {
      int c = i * 256 + tid;
      int row = c >> 3, cc = c & 7;
      int gc = cc ^ (row & 7);
      gl_lds16(Ab + (size_t)row * HC + kt * 64 + gc * 8, lsA + c * 8);
      gl_lds16(Wb + (size_t)row * HC + kt * 64 + gc * 8, lsB + c * 8);
    }
    __syncthreads();  // drains vmcnt for global_load_lds
#pragma unroll
    for (int ks = 0; ks < 2; ++ks) {
      bf16x8 af[4], bfr[4];
#pragma unroll
      for (int mi = 0; mi < 4; mi++) {
        int r = wr * 64 + mi * 16 + l16;
        int cc = (ks * 4 + quad) ^ (r & 7);
        af[mi] = *(const bf16x8*)(lsA + r * 64 + cc * 8);
      }
#pragma unroll
      for (int ni = 0; ni < 4; ni++) {
        int r = wc * 64 + ni * 16 + l16;
        int cc = (ks * 4 + quad) ^ (r & 7);
        bfr[ni] = *(const bf16x8*)(lsB + r * 64 + cc * 8);
      }
#pragma unroll
      for (int mi = 0; mi < 4; mi++)
#pragma unroll
        for (int ni = 0; ni < 4; ni++)
          acc[mi][ni] = __builtin_amdgcn_mfma_f32_16x16x32_bf16(af[mi], bfr[ni], acc[mi][ni], 0, 0, 0);
    }
  }

  // epilogue: C/D layout col = lane&15, row = quad*4 + reg
#pragma unroll
  for (int mi = 0; mi < 4; mi++) {
#pragma unroll
    for (int ni = 0; ni < 4; ni++) {
#pragma unroll
      for (int r = 0; r < 4; r++) {
        int m = bm * 128 + wr * 64 + mi * 16 + quad * 4 + r;
        int n = bn * 128 + wc * 64 + ni * 16 + l16;
        float v = acc[mi][ni][r];
        if (MODE == 0) {
          ((float*)outp)[(size_t)m * HC + n] = v;
        } else if (MODE == 1) {  // [B,H,T,D]: b=m>>8, t=m&255, h=n>>7, d=n&127
          size_t idx = ((((size_t)(m >> 8) * HH + (n >> 7)) * HT + (m & 255)) * HD) + (n & 127);
          ((unsigned short*)outp)[idx] = f2bf(v);
        } else {  // [B,H,D,T]
          size_t idx = ((((size_t)(m >> 8) * HH + (n >> 7)) * HD + (n & 127)) * HT) + (m & 255);
          ((unsigned short*)outp)[idx] = f2bf(v);
        }
      }
    }
  }
}

// ---------------- RoPE (in-place on Q,K in [B,H,T,D]) ----------------
__global__ __launch_bounds__(64) void rope_kernel(unsigned short* __restrict__ Q,
                                                  unsigned short* __restrict__ K) {
  int bht = blockIdx.x;        // (b*H + h)*T + t
  int t = bht & (HT - 1);
  int d = threadIdx.x;         // 0..63
  size_t base = (size_t)bht * HD;
  // inv_freq[d] = 10000^(-d/64) = exp(-d * ln(10000)/64)
  float ang = (float)t * __expf((float)d * (-0.14391156831212787f));
  float c = cosf(ang), s = sinf(ang);
  float q0 = bf2f(Q[base + d]), q1 = bf2f(Q[base + d + 64]);
  Q[base + d]      = f2bf(q0 * c - q1 * s);
  Q[base + d + 64] = f2bf(q1 * c + q0 * s);
  float k0 = bf2f(K[base + d]), k1 = bf2f(K[base + d + 64]);
  K[base + d]      = f2bf(k0 * c - k1 * s);
  K[base + d + 64] = f2bf(k1 * c + k0 * s);
}

// ---------------- causal flash attention ----------------
// One wave per 64 q-rows of one (b,h). Q in [B,H,T,D], K in [B,H,T,D], Vt in [B,H,D,T].
// Y written as [B,T,C] bf16.
__global__ __launch_bounds__(64) void attn_kernel(const unsigned short* __restrict__ Q,
                                                  const unsigned short* __restrict__ K,
                                                  const unsigned short* __restrict__ Vt,
                                                  unsigned short* __restrict__ Y) {
  const int bh = blockIdx.x >> 2;
  const int wq = blockIdx.x & 3;   // which 64-row q block
  const int lane = threadIdx.x;
  const int quad = lane >> 4, l16 = lane & 15;

  const unsigned short* Qh = Q + (size_t)bh * HT * HD;
  const unsigned short* Kh = K + (size_t)bh * HT * HD;
  const unsigned short* Vh = Vt + (size_t)bh * HD * HT;

  // P buffer: [64 rows][72] bf16; row stride 144B = 16B-aligned, ~2-way banks max.
  __shared__ __align__(16) unsigned short P[64 * 72];

  // Q fragments resident: A-layout row m = l16, k = ks*32 + quad*8 .. +7
  bf16x8 qf[4][4];
#pragma unroll
  for (int mi = 0; mi < 4; mi++)
#pragma unroll
    for (int ks = 0; ks < 4; ks++)
      qf[mi][ks] = *(const bf16x8*)(Qh + (size_t)(wq * 64 + mi * 16 + l16) * HD + ks * 32 + quad * 8);

  f32x4 o[4][8];
#pragma unroll
  for (int mi = 0; mi < 4; mi++)
#pragma unroll
    for (int di = 0; di < 8; di++) o[mi][di] = f32x4{0.f, 0.f, 0.f, 0.f};
  float mrow[4][4], lrow[4][4];
#pragma unroll
  for (int mi = 0; mi < 4; mi++)
#pragma unroll
    for (int r = 0; r < 4; r++) { mrow[mi][r] = -1e30f; lrow[mi][r] = 0.f; }

  const float scale = 0.088388347648318447f;  // 1/sqrt(128)

  for (int ct = 0; ct <= wq; ++ct) {
    // S tile 64x64 = Q(64x128) . K^T
    f32x4 s[4][4];
#pragma unroll
    for (int mi = 0; mi < 4; mi++)
#pragma unroll
      for (int ni = 0; ni < 4; ni++) s[mi][ni] = f32x4{0.f, 0.f, 0.f, 0.f};
#pragma unroll
    for (int ks = 0; ks < 4; ks++) {
      bf16x8 kf[4];
#pragma unroll
      for (int ni = 0; ni < 4; ni++)
        kf[ni] = *(const bf16x8*)(Kh + (size_t)(ct * 64 + ni * 16 + l16) * HD + ks * 32 + quad * 8);
#pragma unroll
      for (int mi = 0; mi < 4; mi++)
#pragma unroll
        for (int ni = 0; ni < 4; ni++)
          s[mi][ni] = __builtin_amdgcn_mfma_f32_16x16x32_bf16(qf[mi][ks], kf[ni], s[mi][ni], 0, 0, 0);
    }
    // scale + causal mask (diag tile only: k_abs<=q_abs <=> kc<=qr since ct==wq)
    if (ct == wq) {
#pragma unroll
      for (int mi = 0; mi < 4; mi++)
#pragma unroll
        for (int ni = 0; ni < 4; ni++)
#pragma unroll
          for (int r = 0; r < 4; r++) {
            int qr = mi * 16 + quad * 4 + r;
            int kc = ni * 16 + l16;
            s[mi][ni][r] = (kc <= qr) ? s[mi][ni][r] * scale : -1e30f;
          }
    } else {
#pragma unroll
      for (int mi = 0; mi < 4; mi++)
#pragma unroll
        for (int ni = 0; ni < 4; ni++)
#pragma unroll
          for (int r = 0; r < 4; r++) s[mi][ni][r] *= scale;
    }
    // online softmax per row (row group = 16 lanes sharing quad)
#pragma unroll
    for (int mi = 0; mi < 4; mi++) {
#pragma unroll
      for (int r = 0; r < 4; r++) {
        float v = fmaxf(fmaxf(s[mi][0][r], s[mi][1][r]), fmaxf(s[mi][2][r], s[mi][3][r]));
        v = fmaxf(v, __shfl_xor(v, 1, 64));
        v = fmaxf(v, __shfl_xor(v, 2, 64));
        v = fmaxf(v, __shfl_xor(v, 4, 64));
        v = fmaxf(v, __shfl_xor(v, 8, 64));
        float mnew = fmaxf(mrow[mi][r], v);
        float alpha = __expf(mrow[mi][r] - mnew);
        mrow[mi][r] = mnew;
        float rs = 0.f;
#pragma unroll
        for (int ni = 0; ni < 4; ni++) {
          float e = __expf(s[mi][ni][r] - mnew);
          s[mi][ni][r] = e;
          rs += e;
        }
        rs += __shfl_xor(rs, 1, 64);
        rs += __shfl_xor(rs, 2, 64);
        rs += __shfl_xor(rs, 4, 64);
        rs += __shfl_xor(rs, 8, 64);
        lrow[mi][r] = lrow[mi][r] * alpha + rs;
#pragma unroll
        for (int di = 0; di < 8; di++) o[mi][di][r] *= alpha;
      }
    }
    // P: C-layout -> LDS -> A-layout
    __syncthreads();
#pragma unroll
    for (int mi = 0; mi < 4; mi++)
#pragma unroll
      for (int ni = 0; ni < 4; ni++)
#pragma unroll
        for (int r = 0; r < 4; r++)
          P[(mi * 16 + quad * 4 + r) * 72 + ni * 16 + l16] = f2bf(s[mi][ni][r]);
    __syncthreads();
    // O += P(64x64) . V(64x128)  -- B operand from Vt: n=d, k contiguous
#pragma unroll
    for (int ks = 0; ks < 2; ks++) {
      bf16x8 pf[4];
#pragma unroll
      for (int mi = 0; mi < 4; mi++)
        pf[mi] = *(const bf16x8*)(P + (size_t)(mi * 16 + l16) * 72 + ks * 32 + quad * 8);
#pragma unroll
      for (int di = 0; di < 8; di++) {
        bf16x8 vf = *(const bf16x8*)(Vh + (size_t)(di * 16 + l16) * HT + ct * 64 + ks * 32 + quad * 8);
#pragma unroll
        for (int mi = 0; mi < 4; mi++)
          o[mi][di] = __builtin_amdgcn_mfma_f32_16x16x32_bf16(pf[mi], vf, o[mi][di], 0, 0, 0);
      }
    }
  }

  // normalize + write Y [B,T,C]
  const int b = bh >> 4, h = bh & 15;
#pragma unroll
  for (int mi = 0; mi < 4; mi++) {
#pragma unroll
    for (int r = 0; r < 4; r++) {
      float inv = 1.f / lrow[mi][r];
      int t = wq * 64 + mi * 16 + quad * 4 + r;
      size_t rowb = ((size_t)b * HT + t) * HC + h * HD;
#pragma unroll
      for (int di = 0; di < 8; di++)
        Y[rowb + di * 16 + l16] = f2bf(o[mi][di][r] * inv);
    }
  }
}

// ---------------- launch ----------------
extern "C" void kernel_launch(void* const* d_in, const int* in_sizes, int n_in,
                              void* d_out, int out_size, void* d_ws, size_t ws_size,
                              hipStream_t stream) {
  const float* x  = (const float*)d_in[0];
  const float* wq = (const float*)d_in[1];
  const float* wk = (const float*)d_in[2];
  const float* wv = (const float*)d_in[3];
  const float* wo = (const float*)d_in[4];
  float* out = (float*)d_out;

  char* ws = (char*)d_ws;
  const size_t MB = (size_t)1 << 20;
  unsigned short* wqb = (unsigned short*)(ws + 0 * MB);    // 8 MiB each
  unsigned short* wkb = (unsigned short*)(ws + 8 * MB);
  unsigned short* wvb = (unsigned short*)(ws + 16 * MB);
  unsigned short* wob = (unsigned short*)(ws + 24 * MB);
  unsigned short* xb  = (unsigned short*)(ws + 32 * MB);   // 32 MiB
  unsigned short* Qb  = (unsigned short*)(ws + 64 * MB);   // 32 MiB
  unsigned short* Kb  = (unsigned short*)(ws + 96 * MB);   // 32 MiB
  unsigned short* Vtb = (unsigned short*)(ws + 128 * MB);  // 32 MiB -> 160 MiB total
  unsigned short* Yb  = xb;  // reuse x's bf16 buffer after QKV GEMMs

  const int nw4 = HC * HC / 4;
  const int nx4 = HM * HC / 4;
  cvt_kernel<<<dim3((nx4 + 255) / 256), 256, 0, stream>>>(x, xb, nx4);
  cvt_kernel<<<dim3((nw4 + 255) / 256), 256, 0, stream>>>(wq, wqb, nw4);
  cvt_kernel<<<dim3((nw4 + 255) / 256), 256, 0, stream>>>(wk, wkb, nw4);
  cvt_kernel<<<dim3((nw4 + 255) / 256), 256, 0, stream>>>(wv, wvb, nw4);
  cvt_kernel<<<dim3((nw4 + 255) / 256), 256, 0, stream>>>(wo, wob, nw4);

  dim3 gg(HM / 128, HC / 128);
  gemm_bt<1><<<gg, 256, 0, stream>>>(xb, wqb, Qb);
  gemm_bt<1><<<gg, 256, 0, stream>>>(xb, wkb, Kb);
  gemm_bt<2><<<gg, 256, 0, stream>>>(xb, wvb, Vtb);

  rope_kernel<<<HB * HH * HT, 64, 0, stream>>>(Qb, Kb);

  attn_kernel<<<HB * HH * 4, 64, 0, stream>>>(Qb, Kb, Vtb, Yb);

  gemm_bt<0><<<gg, 256, 0, stream>>>(Yb, wob, out);
}

// Round 2
// 608.091 us; speedup vs baseline: 1.0798x; 1.0798x over previous
//
#include <hip/hip_runtime.h>

#define HB 32
#define HT 256
#define HC 2048
#define HH 16
#define HD 128
#define HM (HB * HT)  // 8192

typedef __bf16 bf16x8 __attribute__((ext_vector_type(8)));
typedef float f32x4 __attribute__((ext_vector_type(4)));

__device__ __forceinline__ unsigned short f2bf(float f) {
  unsigned u = __float_as_uint(f);
  u += 0x7FFFu + ((u >> 16) & 1u);  // round-to-nearest-even
  return (unsigned short)(u >> 16);
}
__device__ __forceinline__ float bf2f(unsigned short h) {
  return __uint_as_float(((unsigned)h) << 16);
}

// ---------------- fused fp32 -> bf16 convert (x + 4 weights) ----------------
// x: 4194304 float4s; each weight: 1048576 float4s. Total 8388608.
__global__ __launch_bounds__(256) void cvt_all(
    const float* __restrict__ x, const float* __restrict__ wq, const float* __restrict__ wk,
    const float* __restrict__ wv, const float* __restrict__ wo,
    unsigned short* __restrict__ xb, unsigned short* __restrict__ wqb,
    unsigned short* __restrict__ wkb, unsigned short* __restrict__ wvb,
    unsigned short* __restrict__ wob) {
  size_t i = (size_t)blockIdx.x * 256 + threadIdx.x;
  const float* src;
  unsigned short* dst;
  size_t off;
  if (i < 4194304) {
    src = x; dst = xb; off = i;
  } else {
    size_t j = i - 4194304;
    int w = (int)(j >> 20);
    off = j & 1048575;
    src = (w == 0) ? wq : (w == 1) ? wk : (w == 2) ? wv : wo;
    dst = (w == 0) ? wqb : (w == 1) ? wkb : (w == 2) ? wvb : wob;
  }
  float4 v = ((const float4*)src)[off];
  ushort4 o;
  o.x = f2bf(v.x); o.y = f2bf(v.y); o.z = f2bf(v.z); o.w = f2bf(v.w);
  ((ushort4*)dst)[off] = o;
}

// ---------------- GEMM core: 128x128 tile, BK=64, XOR-swizzled LDS ----------------
__device__ __forceinline__ void gl_lds16(const unsigned short* g, unsigned short* l) {
  __builtin_amdgcn_global_load_lds((const __attribute__((address_space(1))) void*)g,
                                   (__attribute__((address_space(3))) void*)l, 16, 0, 0);
}

__device__ __forceinline__ void gemm_core(const unsigned short* __restrict__ Ab,
                                          const unsigned short* __restrict__ Wb,
                                          unsigned short* lsA, unsigned short* lsB,
                                          f32x4 acc[4][4], int tid) {
  const int lane = tid & 63, wave = tid >> 6;
  const int quad = lane >> 4, l16 = lane & 15;
  const int wr = wave >> 1, wc = wave & 1;
  for (int kt = 0; kt < HC / 64; ++kt) {
    __syncthreads();
#pragma unroll
    for (int i = 0; i < 4; i++) {
      int c = i * 256 + tid;
      int row = c >> 3, cc = c & 7;
      int gc = cc ^ (row & 7);
      gl_lds16(Ab + (size_t)row * HC + kt * 64 + gc * 8, lsA + c * 8);
      gl_lds16(Wb + (size_t)row * HC + kt * 64 + gc * 8, lsB + c * 8);
    }
    __syncthreads();
#pragma unroll
    for (int ks = 0; ks < 2; ++ks) {
      bf16x8 af[4], bfr[4];
#pragma unroll
      for (int mi = 0; mi < 4; mi++) {
        int r = wr * 64 + mi * 16 + l16;
        int cc = (ks * 4 + quad) ^ (r & 7);
        af[mi] = *(const bf16x8*)(lsA + r * 64 + cc * 8);
      }
#pragma unroll
      for (int ni = 0; ni < 4; ni++) {
        int r = wc * 64 + ni * 16 + l16;
        int cc = (ks * 4 + quad) ^ (r & 7);
        bfr[ni] = *(const bf16x8*)(lsB + r * 64 + cc * 8);
      }
#pragma unroll
      for (int mi = 0; mi < 4; mi++)
#pragma unroll
        for (int ni = 0; ni < 4; ni++)
          acc[mi][ni] = __builtin_amdgcn_mfma_f32_16x16x32_bf16(af[mi], bfr[ni], acc[mi][ni], 0, 0, 0);
    }
  }
}

// Output projection GEMM: fp32 out [M, 2048]
__global__ __launch_bounds__(256) void gemm_out(const unsigned short* __restrict__ A,
                                                const unsigned short* __restrict__ W,
                                                float* __restrict__ outp) {
  __shared__ __align__(16) unsigned short lsA[128 * 64];
  __shared__ __align__(16) unsigned short lsB[128 * 64];
  const int tid = threadIdx.x;
  const int lane = tid & 63, wave = tid >> 6;
  const int quad = lane >> 4, l16 = lane & 15;
  const int wr = wave >> 1, wc = wave & 1;
  const int bm = blockIdx.x, bn = blockIdx.y;

  f32x4 acc[4][4];
#pragma unroll
  for (int i = 0; i < 4; i++)
#pragma unroll
    for (int j = 0; j < 4; j++) acc[i][j] = f32x4{0.f, 0.f, 0.f, 0.f};

  gemm_core(A + (size_t)bm * 128 * HC, W + (size_t)bn * 128 * HC, lsA, lsB, acc, tid);

#pragma unroll
  for (int mi = 0; mi < 4; mi++)
#pragma unroll
    for (int ni = 0; ni < 4; ni++)
#pragma unroll
      for (int r = 0; r < 4; r++) {
        int m = bm * 128 + wr * 64 + mi * 16 + quad * 4 + r;
        int n = bn * 128 + wc * 64 + ni * 16 + l16;
        outp[(size_t)m * HC + n] = acc[mi][ni][r];
      }
}

// Fused QKV GEMM: grid (64, 48); bn>>4 selects {Q,K,V}. Q,K -> [B,H,T,D]; V -> [B,H,D,T].
__global__ __launch_bounds__(256) void gemm_qkv(const unsigned short* __restrict__ A,
                                                const unsigned short* __restrict__ W0,
                                                const unsigned short* __restrict__ W1,
                                                const unsigned short* __restrict__ W2,
                                                unsigned short* __restrict__ Qo,
                                                unsigned short* __restrict__ Ko,
                                                unsigned short* __restrict__ Vto) {
  __shared__ __align__(16) unsigned short lsA[128 * 64];
  __shared__ __align__(16) unsigned short lsB[128 * 64];
  const int tid = threadIdx.x;
  const int lane = tid & 63, wave = tid >> 6;
  const int quad = lane >> 4, l16 = lane & 15;
  const int wr = wave >> 1, wc = wave & 1;
  const int bm = blockIdx.x;
  const int which = blockIdx.y >> 4;
  const int bn = blockIdx.y & 15;
  const unsigned short* W = (which == 0) ? W0 : (which == 1) ? W1 : W2;
  unsigned short* outp = (which == 0) ? Qo : (which == 1) ? Ko : Vto;

  f32x4 acc[4][4];
#pragma unroll
  for (int i = 0; i < 4; i++)
#pragma unroll
    for (int j = 0; j < 4; j++) acc[i][j] = f32x4{0.f, 0.f, 0.f, 0.f};

  gemm_core(A + (size_t)bm * 128 * HC, W + (size_t)bn * 128 * HC, lsA, lsB, acc, tid);

#pragma unroll
  for (int mi = 0; mi < 4; mi++)
#pragma unroll
    for (int ni = 0; ni < 4; ni++)
#pragma unroll
      for (int r = 0; r < 4; r++) {
        int m = bm * 128 + wr * 64 + mi * 16 + quad * 4 + r;   // b*256 + t
        int n = bn * 128 + wc * 64 + ni * 16 + l16;            // h*128 + d
        unsigned short v = f2bf(acc[mi][ni][r]);
        if (which < 2) {  // [B,H,T,D]
          size_t idx = ((((size_t)(m >> 8) * HH + (n >> 7)) * HT + (m & 255)) * HD) + (n & 127);
          outp[idx] = v;
        } else {  // [B,H,D,T]
          size_t idx = ((((size_t)(m >> 8) * HH + (n >> 7)) * HD + (n & 127)) * HT) + (m & 255);
          outp[idx] = v;
        }
      }
}

// ---------------- RoPE (in-place on Q,K in [B,H,T,D]) ----------------
// 16 threads per row; each thread rotates 4 (d, d+64) pairs via ushort4.
__global__ __launch_bounds__(256) void rope_kernel(unsigned short* __restrict__ Q,
                                                   unsigned short* __restrict__ K) {
  int idx = blockIdx.x * 256 + threadIdx.x;
  int row = idx >> 4;          // (b*H + h)*T + t, 131072 rows
  int dq = (idx & 15) * 4;
  int t = row & (HT - 1);
  size_t base = (size_t)row * HD;

  ushort4 q0 = *(const ushort4*)(Q + base + dq);
  ushort4 q1 = *(const ushort4*)(Q + base + 64 + dq);
  ushort4 k0 = *(const ushort4*)(K + base + dq);
  ushort4 k1 = *(const ushort4*)(K + base + 64 + dq);

  float c[4], s[4];
#pragma unroll
  for (int j = 0; j < 4; j++) {
    float ang = (float)t * __expf((float)(dq + j) * (-0.14391156831212787f));
    c[j] = cosf(ang);
    s[j] = sinf(ang);
  }
  unsigned short* q0p = (unsigned short*)&q0;
  unsigned short* q1p = (unsigned short*)&q1;
  unsigned short* k0p = (unsigned short*)&k0;
  unsigned short* k1p = (unsigned short*)&k1;
#pragma unroll
  for (int j = 0; j < 4; j++) {
    float a = bf2f(q0p[j]), b = bf2f(q1p[j]);
    q0p[j] = f2bf(a * c[j] - b * s[j]);
    q1p[j] = f2bf(b * c[j] + a * s[j]);
    float ka = bf2f(k0p[j]), kb = bf2f(k1p[j]);
    k0p[j] = f2bf(ka * c[j] - kb * s[j]);
    k1p[j] = f2bf(kb * c[j] + ka * s[j]);
  }
  *(ushort4*)(Q + base + dq) = q0;
  *(ushort4*)(Q + base + 64 + dq) = q1;
  *(ushort4*)(K + base + dq) = k0;
  *(ushort4*)(K + base + 64 + dq) = k1;
}

// ---------------- causal flash attention ----------------
// Block = 4 waves; block handles 64 q-rows of one (b,h); wave owns 16 q-rows.
// Q,K in [B,H,T,D], Vt in [B,H,D,T]. Y written as [B,T,C] bf16.
// Heavy-first ordering: first 512 blocks take wq=3 (longest causal range).
__global__ __launch_bounds__(256, 4) void attn_kernel(const unsigned short* __restrict__ Q,
                                                      const unsigned short* __restrict__ K,
                                                      const unsigned short* __restrict__ Vt,
                                                      unsigned short* __restrict__ Y) {
  const int g = blockIdx.x;
  const int wq = 3 - (g >> 9);
  const int bh = g & 511;
  const int wave = threadIdx.x >> 6;
  const int lane = threadIdx.x & 63;
  const int quad = lane >> 4, l16 = lane & 15;

  const unsigned short* Qh = Q + (size_t)bh * HT * HD;
  const unsigned short* Kh = K + (size_t)bh * HT * HD;
  const unsigned short* Vh = Vt + (size_t)bh * HD * HT;

  // per-wave private P region -> no __syncthreads in the ct loop
  __shared__ __align__(16) unsigned short P[4][16 * 72];
  unsigned short* Pw = P[wave];

  const int qrow = wq * 64 + wave * 16;

  bf16x8 qf[4];
#pragma unroll
  for (int ks = 0; ks < 4; ks++)
    qf[ks] = *(const bf16x8*)(Qh + (size_t)(qrow + l16) * HD + ks * 32 + quad * 8);

  f32x4 o[8];
#pragma unroll
  for (int di = 0; di < 8; di++) o[di] = f32x4{0.f, 0.f, 0.f, 0.f};
  float mrow[4], lrow[4];
#pragma unroll
  for (int r = 0; r < 4; r++) { mrow[r] = -1e30f; lrow[r] = 0.f; }

  const float scale = 0.088388347648318447f;  // 1/sqrt(128)

  for (int ct = 0; ct <= wq; ++ct) {
    f32x4 s[4];
#pragma unroll
    for (int ni = 0; ni < 4; ni++) s[ni] = f32x4{0.f, 0.f, 0.f, 0.f};
    const int nimax = (ct == wq) ? wave : 3;  // skip fully-masked diagonal sub-tiles
#pragma unroll
    for (int ks = 0; ks < 4; ks++) {
#pragma unroll
      for (int ni = 0; ni < 4; ni++) {
        if (ni <= nimax) {
          bf16x8 kf = *(const bf16x8*)(Kh + (size_t)(ct * 64 + ni * 16 + l16) * HD + ks * 32 + quad * 8);
          s[ni] = __builtin_amdgcn_mfma_f32_16x16x32_bf16(qf[ks], kf, s[ni], 0, 0, 0);
        }
      }
    }
    if (ct == wq) {
#pragma unroll
      for (int ni = 0; ni < 4; ni++)
#pragma unroll
        for (int r = 0; r < 4; r++) {
          int qr = wave * 16 + quad * 4 + r;  // row within 64-tile
          int kc = ni * 16 + l16;             // col within 64-tile
          s[ni][r] = (kc <= qr) ? s[ni][r] * scale : -1e30f;
        }
    } else {
#pragma unroll
      for (int ni = 0; ni < 4; ni++)
#pragma unroll
        for (int r = 0; r < 4; r++) s[ni][r] *= scale;
    }
    // online softmax, rows = quad*4 + r, reduce across 16 l16 lanes
#pragma unroll
    for (int r = 0; r < 4; r++) {
      float v = fmaxf(fmaxf(s[0][r], s[1][r]), fmaxf(s[2][r], s[3][r]));
      v = fmaxf(v, __shfl_xor(v, 1, 64));
      v = fmaxf(v, __shfl_xor(v, 2, 64));
      v = fmaxf(v, __shfl_xor(v, 4, 64));
      v = fmaxf(v, __shfl_xor(v, 8, 64));
      float mnew = fmaxf(mrow[r], v);
      float alpha = __expf(mrow[r] - mnew);
      mrow[r] = mnew;
      float rs = 0.f;
#pragma unroll
      for (int ni = 0; ni < 4; ni++) {
        float e = __expf(s[ni][r] - mnew);
        s[ni][r] = e;
        rs += e;
      }
      rs += __shfl_xor(rs, 1, 64);
      rs += __shfl_xor(rs, 2, 64);
      rs += __shfl_xor(rs, 4, 64);
      rs += __shfl_xor(rs, 8, 64);
      lrow[r] = lrow[r] * alpha + rs;
#pragma unroll
      for (int di = 0; di < 8; di++) o[di][r] *= alpha;
    }
    // P: C-layout -> per-wave LDS -> A-layout (no barrier: wave-private region)
#pragma unroll
    for (int ni = 0; ni < 4; ni++)
#pragma unroll
      for (int r = 0; r < 4; r++)
        Pw[(quad * 4 + r) * 72 + ni * 16 + l16] = f2bf(s[ni][r]);
    // O += P(16x64) . V(64x128)
#pragma unroll
    for (int ks = 0; ks < 2; ks++) {
      bf16x8 pf = *(const bf16x8*)(Pw + (size_t)l16 * 72 + ks * 32 + quad * 8);
#pragma unroll
      for (int di = 0; di < 8; di++) {
        bf16x8 vf = *(const bf16x8*)(Vh + (size_t)(di * 16 + l16) * HT + ct * 64 + ks * 32 + quad * 8);
        o[di] = __builtin_amdgcn_mfma_f32_16x16x32_bf16(pf, vf, o[di], 0, 0, 0);
      }
    }
  }

  // normalize + write Y [B,T,C]
  const int b = bh >> 4, h = bh & 15;
#pragma unroll
  for (int r = 0; r < 4; r++) {
    float inv = 1.f / lrow[r];
    int t = qrow + quad * 4 + r;
    size_t rowb = ((size_t)b * HT + t) * HC + h * HD;
#pragma unroll
    for (int di = 0; di < 8; di++)
      Y[rowb + di * 16 + l16] = f2bf(o[di][r] * inv);
  }
}

// ---------------- launch ----------------
extern "C" void kernel_launch(void* const* d_in, const int* in_sizes, int n_in,
                              void* d_out, int out_size, void* d_ws, size_t ws_size,
                              hipStream_t stream) {
  const float* x  = (const float*)d_in[0];
  const float* wq = (const float*)d_in[1];
  const float* wk = (const float*)d_in[2];
  const float* wv = (const float*)d_in[3];
  const float* wo = (const float*)d_in[4];
  float* out = (float*)d_out;

  char* ws = (char*)d_ws;
  const size_t MB = (size_t)1 << 20;
  unsigned short* wqb = (unsigned short*)(ws + 0 * MB);    // 8 MiB each
  unsigned short* wkb = (unsigned short*)(ws + 8 * MB);
  unsigned short* wvb = (unsigned short*)(ws + 16 * MB);
  unsigned short* wob = (unsigned short*)(ws + 24 * MB);
  unsigned short* xb  = (unsigned short*)(ws + 32 * MB);   // 32 MiB
  unsigned short* Qb  = (unsigned short*)(ws + 64 * MB);   // 32 MiB
  unsigned short* Kb  = (unsigned short*)(ws + 96 * MB);   // 32 MiB
  unsigned short* Vtb = (unsigned short*)(ws + 128 * MB);  // 32 MiB -> 160 MiB total
  unsigned short* Yb  = xb;  // reuse x's bf16 buffer after QKV GEMMs

  cvt_all<<<32768, 256, 0, stream>>>(x, wq, wk, wv, wo, xb, wqb, wkb, wvb, wob);

  gemm_qkv<<<dim3(HM / 128, 48), 256, 0, stream>>>(xb, wqb, wkb, wvb, Qb, Kb, Vtb);

  rope_kernel<<<8192, 256, 0, stream>>>(Qb, Kb);

  attn_kernel<<<2048, 256, 0, stream>>>(Qb, Kb, Vtb, Yb);

  gemm_out<<<dim3(HM / 128, HC / 128), 256, 0, stream>>>(Yb, wob, out);
}

// Round 3
// 537.023 us; speedup vs baseline: 1.2226x; 1.1323x over previous
//
#include <hip/hip_runtime.h>

#define HB 32
#define HT 256
#define HC 2048
#define HH 16
#define HD 128
#define HM (HB * HT)  // 8192

typedef __bf16 bf16x8 __attribute__((ext_vector_type(8)));
typedef float f32x4 __attribute__((ext_vector_type(4)));
typedef float f32x16 __attribute__((ext_vector_type(16)));

__device__ __forceinline__ unsigned short f2bf(float f) {
  unsigned u = __float_as_uint(f);
  u += 0x7FFFu + ((u >> 16) & 1u);  // round-to-nearest-even
  return (unsigned short)(u >> 16);
}
__device__ __forceinline__ float bf2f(unsigned short h) {
  return __uint_as_float(((unsigned)h) << 16);
}

// ---------------- fused fp32 -> bf16 convert (x + 4 weights) ----------------
__global__ __launch_bounds__(256) void cvt_all(
    const float* __restrict__ x, const float* __restrict__ wq, const float* __restrict__ wk,
    const float* __restrict__ wv, const float* __restrict__ wo,
    unsigned short* __restrict__ xb, unsigned short* __restrict__ wqb,
    unsigned short* __restrict__ wkb, unsigned short* __restrict__ wvb,
    unsigned short* __restrict__ wob) {
  size_t i = (size_t)blockIdx.x * 256 + threadIdx.x;
  const float* src;
  unsigned short* dst;
  size_t off;
  if (i < 4194304) {
    src = x; dst = xb; off = i;
  } else {
    size_t j = i - 4194304;
    int w = (int)(j >> 20);
    off = j & 1048575;
    src = (w == 0) ? wq : (w == 1) ? wk : (w == 2) ? wv : wo;
    dst = (w == 0) ? wqb : (w == 1) ? wkb : (w == 2) ? wvb : wob;
  }
  float4 v = ((const float4*)src)[off];
  ushort4 o;
  o.x = f2bf(v.x); o.y = f2bf(v.y); o.z = f2bf(v.z); o.w = f2bf(v.w);
  ((ushort4*)dst)[off] = o;
}

// ---------------- GEMM core: 128x128 tile, BK=64, 32x32x16 MFMA ----------------
__device__ __forceinline__ void gl_lds16(const unsigned short* g, unsigned short* l) {
  __builtin_amdgcn_global_load_lds((const __attribute__((address_space(1))) void*)g,
                                   (__attribute__((address_space(3))) void*)l, 16, 0, 0);
}

// Wave output: rows wr*64 + mi*32 + l31, cols nj*64 + wc*32 + l31 (nj splits the
// 128-col tile into two 64-halves so RoPE pairs (d, d+64) share a lane/reg).
__device__ __forceinline__ void gemm_core32(const unsigned short* __restrict__ Ab,
                                            const unsigned short* __restrict__ Wb,
                                            unsigned short* lsA, unsigned short* lsB,
                                            f32x16 acc[2][2], int tid) {
  const int lane = tid & 63, wave = tid >> 6;
  const int l31 = lane & 31, half = lane >> 5;
  const int wr = wave >> 1, wc = wave & 1;
  for (int kt = 0; kt < HC / 64; ++kt) {
    __syncthreads();
#pragma unroll
    for (int i = 0; i < 4; i++) {
      int c = i * 256 + tid;
      int row = c >> 3, cc = c & 7;
      int gc = cc ^ (row & 7);
      gl_lds16(Ab + (size_t)row * HC + kt * 64 + gc * 8, lsA + c * 8);
      gl_lds16(Wb + (size_t)row * HC + kt * 64 + gc * 8, lsB + c * 8);
    }
    __syncthreads();
#pragma unroll
    for (int ks = 0; ks < 4; ++ks) {
      const int g = ks * 2 + half;
      bf16x8 af[2], bfr[2];
#pragma unroll
      for (int mi = 0; mi < 2; mi++) {
        int r = wr * 64 + mi * 32 + l31;
        int cc = g ^ (r & 7);
        af[mi] = *(const bf16x8*)(lsA + r * 64 + cc * 8);
      }
#pragma unroll
      for (int nj = 0; nj < 2; nj++) {
        int r = nj * 64 + wc * 32 + l31;
        int cc = g ^ (r & 7);
        bfr[nj] = *(const bf16x8*)(lsB + r * 64 + cc * 8);
      }
#pragma unroll
      for (int mi = 0; mi < 2; mi++)
#pragma unroll
        for (int nj = 0; nj < 2; nj++)
          acc[mi][nj] = __builtin_amdgcn_mfma_f32_32x32x16_bf16(af[mi], bfr[nj], acc[mi][nj], 0, 0, 0);
    }
  }
}

// Output projection GEMM: fp32 out [M, 2048]
__global__ __launch_bounds__(256) void gemm_out(const unsigned short* __restrict__ A,
                                                const unsigned short* __restrict__ W,
                                                float* __restrict__ outp) {
  __shared__ __align__(16) unsigned short lsA[128 * 64];
  __shared__ __align__(16) unsigned short lsB[128 * 64];
  const int tid = threadIdx.x;
  const int lane = tid & 63, wave = tid >> 6;
  const int l31 = lane & 31, half = lane >> 5;
  const int wr = wave >> 1, wc = wave & 1;
  const int bm = blockIdx.x, bn = blockIdx.y;

  f32x16 acc[2][2];
#pragma unroll
  for (int i = 0; i < 2; i++)
#pragma unroll
    for (int j = 0; j < 2; j++)
#pragma unroll
      for (int r = 0; r < 16; r++) acc[i][j][r] = 0.f;

  gemm_core32(A + (size_t)bm * 128 * HC, W + (size_t)bn * 128 * HC, lsA, lsB, acc, tid);

#pragma unroll
  for (int mi = 0; mi < 2; mi++)
#pragma unroll
    for (int nj = 0; nj < 2; nj++)
#pragma unroll
      for (int g = 0; g < 4; g++)
#pragma unroll
        for (int rr = 0; rr < 4; rr++) {
          int m = bm * 128 + wr * 64 + mi * 32 + rr + 8 * g + 4 * half;
          int n = bn * 128 + nj * 64 + wc * 32 + l31;
          outp[(size_t)m * HC + n] = acc[mi][nj][g * 4 + rr];
        }
}

// Fused QKV GEMM: grid (64, 48); blockIdx.y>>4 selects {Q,K,V}.
// Q,K -> [B,H,T,D] with RoPE fused; V -> [B,H,D,T] via operand swap (coalesced).
__global__ __launch_bounds__(256) void gemm_qkv(const unsigned short* __restrict__ A,
                                                const unsigned short* __restrict__ W0,
                                                const unsigned short* __restrict__ W1,
                                                const unsigned short* __restrict__ W2,
                                                unsigned short* __restrict__ Qo,
                                                unsigned short* __restrict__ Ko,
                                                unsigned short* __restrict__ Vto) {
  __shared__ __align__(16) unsigned short lsA[128 * 64];
  __shared__ __align__(16) unsigned short lsB[128 * 64];
  const int tid = threadIdx.x;
  const int lane = tid & 63, wave = tid >> 6;
  const int l31 = lane & 31, half = lane >> 5;
  const int wr = wave >> 1, wc = wave & 1;
  const int bm = blockIdx.x;
  const int which = blockIdx.y >> 4;
  const int bn = blockIdx.y & 15;

  f32x16 acc[2][2];
#pragma unroll
  for (int i = 0; i < 2; i++)
#pragma unroll
    for (int j = 0; j < 2; j++)
#pragma unroll
      for (int r = 0; r < 16; r++) acc[i][j][r] = 0.f;

  if (which < 2) {
    const unsigned short* W = (which == 0) ? W0 : W1;
    unsigned short* outp = (which == 0) ? Qo : Ko;
    gemm_core32(A + (size_t)bm * 128 * HC, W + (size_t)bn * 128 * HC, lsA, lsB, acc, tid);
    // epilogue with fused RoPE: d_lo = wc*32+l31 (nj=0), d_hi = d_lo+64 (nj=1)
    const int dlo = wc * 32 + l31;
    const float invf = __expf((float)dlo * (-0.14391156831212787f));
    const int h = bn;
#pragma unroll
    for (int mi = 0; mi < 2; mi++)
#pragma unroll
      for (int g = 0; g < 4; g++)
#pragma unroll
        for (int rr = 0; rr < 4; rr++) {
          int m = bm * 128 + wr * 64 + mi * 32 + rr + 8 * g + 4 * half;
          int t = m & 255, b = m >> 8;
          float ang = (float)t * invf;
          float sn, cs;
          __sincosf(ang, &sn, &cs);
          int reg = g * 4 + rr;
          float lo = acc[mi][0][reg], hi = acc[mi][1][reg];
          size_t base = (((size_t)b * HH + h) * HT + t) * HD;
          outp[base + dlo] = f2bf(lo * cs - hi * sn);
          outp[base + 64 + dlo] = f2bf(hi * cs + lo * sn);
        }
  } else {
    // V^T: A-operand = wv tile, B-operand = x tile; output rows = channels (h,d)
    gemm_core32(W2 + (size_t)bn * 128 * HC, A + (size_t)bm * 128 * HC, lsA, lsB, acc, tid);
    const int h = bn;
#pragma unroll
    for (int mi = 0; mi < 2; mi++)
#pragma unroll
      for (int nj = 0; nj < 2; nj++)
#pragma unroll
        for (int g = 0; g < 4; g++)
#pragma unroll
          for (int rr = 0; rr < 4; rr++) {
            int d = wr * 64 + mi * 32 + rr + 8 * g + 4 * half;
            int np = bm * 128 + nj * 64 + wc * 32 + l31;
            int b = np >> 8, t = np & 255;
            Vto[(((size_t)b * HH + h) * HD + d) * HT + t] = f2bf(acc[mi][nj][g * 4 + rr]);
          }
  }
}

// ---------------- causal flash attention ----------------
// Block = 4 waves; block handles 64 q-rows of one (b,h); wave owns 16 q-rows.
// Q,K in [B,H,T,D] (pre-RoPEd), Vt in [B,H,D,T]. Y written as [B,T,C] bf16.
__global__ __launch_bounds__(256, 4) void attn_kernel(const unsigned short* __restrict__ Q,
                                                      const unsigned short* __restrict__ K,
                                                      const unsigned short* __restrict__ Vt,
                                                      unsigned short* __restrict__ Y) {
  const int g = blockIdx.x;
  const int wq = 3 - (g >> 9);
  const int bh = g & 511;
  const int wave = threadIdx.x >> 6;
  const int lane = threadIdx.x & 63;
  const int quad = lane >> 4, l16 = lane & 15;

  const unsigned short* Qh = Q + (size_t)bh * HT * HD;
  const unsigned short* Kh = K + (size_t)bh * HT * HD;
  const unsigned short* Vh = Vt + (size_t)bh * HD * HT;

  __shared__ __align__(16) unsigned short P[4][16 * 72];
  unsigned short* Pw = P[wave];

  const int qrow = wq * 64 + wave * 16;

  bf16x8 qf[4];
#pragma unroll
  for (int ks = 0; ks < 4; ks++)
    qf[ks] = *(const bf16x8*)(Qh + (size_t)(qrow + l16) * HD + ks * 32 + quad * 8);

  f32x4 o[8];
#pragma unroll
  for (int di = 0; di < 8; di++) o[di] = f32x4{0.f, 0.f, 0.f, 0.f};
  float mrow[4], lrow[4];
#pragma unroll
  for (int r = 0; r < 4; r++) { mrow[r] = -1e30f; lrow[r] = 0.f; }

  const float scale = 0.088388347648318447f;  // 1/sqrt(128)

  for (int ct = 0; ct <= wq; ++ct) {
    f32x4 s[4];
#pragma unroll
    for (int ni = 0; ni < 4; ni++) s[ni] = f32x4{0.f, 0.f, 0.f, 0.f};
    const int nimax = (ct == wq) ? wave : 3;
#pragma unroll
    for (int ks = 0; ks < 4; ks++) {
#pragma unroll
      for (int ni = 0; ni < 4; ni++) {
        if (ni <= nimax) {
          bf16x8 kf = *(const bf16x8*)(Kh + (size_t)(ct * 64 + ni * 16 + l16) * HD + ks * 32 + quad * 8);
          s[ni] = __builtin_amdgcn_mfma_f32_16x16x32_bf16(qf[ks], kf, s[ni], 0, 0, 0);
        }
      }
    }
    if (ct == wq) {
#pragma unroll
      for (int ni = 0; ni < 4; ni++)
#pragma unroll
        for (int r = 0; r < 4; r++) {
          int qr = wave * 16 + quad * 4 + r;
          int kc = ni * 16 + l16;
          s[ni][r] = (kc <= qr) ? s[ni][r] * scale : -1e30f;
        }
    } else {
#pragma unroll
      for (int ni = 0; ni < 4; ni++)
#pragma unroll
        for (int r = 0; r < 4; r++) s[ni][r] *= scale;
    }
#pragma unroll
    for (int r = 0; r < 4; r++) {
      float v = fmaxf(fmaxf(s[0][r], s[1][r]), fmaxf(s[2][r], s[3][r]));
      v = fmaxf(v, __shfl_xor(v, 1, 64));
      v = fmaxf(v, __shfl_xor(v, 2, 64));
      v = fmaxf(v, __shfl_xor(v, 4, 64));
      v = fmaxf(v, __shfl_xor(v, 8, 64));
      float mnew = fmaxf(mrow[r], v);
      float alpha = __expf(mrow[r] - mnew);
      mrow[r] = mnew;
      float rs = 0.f;
#pragma unroll
      for (int ni = 0; ni < 4; ni++) {
        float e = __expf(s[ni][r] - mnew);
        s[ni][r] = e;
        rs += e;
      }
      rs += __shfl_xor(rs, 1, 64);
      rs += __shfl_xor(rs, 2, 64);
      rs += __shfl_xor(rs, 4, 64);
      rs += __shfl_xor(rs, 8, 64);
      lrow[r] = lrow[r] * alpha + rs;
#pragma unroll
      for (int di = 0; di < 8; di++) o[di][r] *= alpha;
    }
#pragma unroll
    for (int ni = 0; ni < 4; ni++)
#pragma unroll
      for (int r = 0; r < 4; r++)
        Pw[(quad * 4 + r) * 72 + ni * 16 + l16] = f2bf(s[ni][r]);
#pragma unroll
    for (int ks = 0; ks < 2; ks++) {
      bf16x8 pf = *(const bf16x8*)(Pw + (size_t)l16 * 72 + ks * 32 + quad * 8);
#pragma unroll
      for (int di = 0; di < 8; di++) {
        bf16x8 vf = *(const bf16x8*)(Vh + (size_t)(di * 16 + l16) * HT + ct * 64 + ks * 32 + quad * 8);
        o[di] = __builtin_amdgcn_mfma_f32_16x16x32_bf16(pf, vf, o[di], 0, 0, 0);
      }
    }
  }

  const int b = bh >> 4, h = bh & 15;
#pragma unroll
  for (int r = 0; r < 4; r++) {
    float inv = 1.f / lrow[r];
    int t = qrow + quad * 4 + r;
    size_t rowb = ((size_t)b * HT + t) * HC + h * HD;
#pragma unroll
    for (int di = 0; di < 8; di++)
      Y[rowb + di * 16 + l16] = f2bf(o[di][r] * inv);
  }
}

// ---------------- launch ----------------
extern "C" void kernel_launch(void* const* d_in, const int* in_sizes, int n_in,
                              void* d_out, int out_size, void* d_ws, size_t ws_size,
                              hipStream_t stream) {
  const float* x  = (const float*)d_in[0];
  const float* wq = (const float*)d_in[1];
  const float* wk = (const float*)d_in[2];
  const float* wv = (const float*)d_in[3];
  const float* wo = (const float*)d_in[4];
  float* out = (float*)d_out;

  char* ws = (char*)d_ws;
  const size_t MB = (size_t)1 << 20;
  unsigned short* wqb = (unsigned short*)(ws + 0 * MB);
  unsigned short* wkb = (unsigned short*)(ws + 8 * MB);
  unsigned short* wvb = (unsigned short*)(ws + 16 * MB);
  unsigned short* wob = (unsigned short*)(ws + 24 * MB);
  unsigned short* xb  = (unsigned short*)(ws + 32 * MB);
  unsigned short* Qb  = (unsigned short*)(ws + 64 * MB);
  unsigned short* Kb  = (unsigned short*)(ws + 96 * MB);
  unsigned short* Vtb = (unsigned short*)(ws + 128 * MB);
  unsigned short* Yb  = xb;  // reuse x's bf16 buffer after QKV GEMMs

  cvt_all<<<32768, 256, 0, stream>>>(x, wq, wk, wv, wo, xb, wqb, wkb, wvb, wob);

  gemm_qkv<<<dim3(HM / 128, 48), 256, 0, stream>>>(xb, wqb, wkb, wvb, Qb, Kb, Vtb);

  attn_kernel<<<2048, 256, 0, stream>>>(Qb, Kb, Vtb, Yb);

  gemm_out<<<dim3(HM / 128, HC / 128), 256, 0, stream>>>(Yb, wob, out);
}